// Round 13
// baseline (106.147 us; speedup 1.0000x reference)
//
#include <hip/hip_runtime.h>

typedef __attribute__((ext_vector_type(8))) short s16x8;
typedef __attribute__((ext_vector_type(4))) float f32x4;
typedef unsigned short u16;

#define DEV __device__ __forceinline__

DEV u16 f2bf(float f) {
    unsigned u = __builtin_bit_cast(unsigned, f);
    unsigned r = u + 0x7fffu + ((u >> 16) & 1u);
    return (u16)(r >> 16);
}

DEV float exp2a(float x) {
    float r;
    asm("v_exp_f32 %0, %1" : "=v"(r) : "v"(x));
    return r;
}

DEV unsigned cvtpk(float lo, float hi) {
    unsigned r;
    asm("v_cvt_pk_bf16_f32 %0, %1, %2" : "=v"(r) : "v"(lo), "v"(hi));
    return r;
}

DEV void gload_lds16(const void* g, void* l) {
    __builtin_amdgcn_global_load_lds(
        (const __attribute__((address_space(1))) unsigned int*)g,
        (__attribute__((address_space(3))) unsigned int*)l, 16, 0, 0);
}

DEV f32x4 mfma16(s16x8 a, s16x8 b, f32x4 c) {
    return __builtin_amdgcn_mfma_f32_16x16x32_bf16(a, b, c, 0, 0, 0);
}

template <int N>
DEV void vmwait() {
    asm volatile("s_waitcnt vmcnt(%0)" ::"n"(N) : "memory");
}

// ---------------- LayerNorm: f32 in -> bf16 out, one block per row ----------------
__global__ __launch_bounds__(256) void ln_kernel(const float* __restrict__ x,
                                                 const float* __restrict__ g,
                                                 const float* __restrict__ b,
                                                 u16* __restrict__ xn) {
    const int row = blockIdx.x, t = threadIdx.x;
    const float4 v = *(const float4*)(x + (size_t)row * 1024 + t * 4);
    float s1 = v.x + v.y + v.z + v.w;
    float s2 = v.x * v.x + v.y * v.y + v.z * v.z + v.w * v.w;
#pragma unroll
    for (int d = 1; d < 64; d <<= 1) {
        s1 += __shfl_xor(s1, d);
        s2 += __shfl_xor(s2, d);
    }
    __shared__ float red[8];
    if ((t & 63) == 0) { red[(t >> 6) * 2] = s1; red[(t >> 6) * 2 + 1] = s2; }
    __syncthreads();
    s1 = red[0] + red[2] + red[4] + red[6];
    s2 = red[1] + red[3] + red[5] + red[7];
    const float mu = s1 * (1.0f / 1024.0f);
    const float var = s2 * (1.0f / 1024.0f) - mu * mu;
    const float rs = rsqrtf(var + 1e-5f);
    const float4 gv = *(const float4*)(g + t * 4);
    const float4 bv = *(const float4*)(b + t * 4);
    ushort4 o;
    o.x = f2bf((v.x - mu) * rs * gv.x + bv.x);
    o.y = f2bf((v.y - mu) * rs * gv.y + bv.y);
    o.z = f2bf((v.z - mu) * rs * gv.z + bv.z);
    o.w = f2bf((v.w - mu) * rs * gv.w + bv.w);
    *(ushort4*)(xn + (size_t)row * 1024 + t * 4) = o;
}

// -------- Weight transpose + cast: src f32 [1024 K][ld N] -> dst bf16 [N][1024] --------
__global__ __launch_bounds__(256) void transpose_w(const float* __restrict__ src0,
                                                   const float* __restrict__ src1,
                                                   u16* __restrict__ dst, int ld) {
    __shared__ float tile[64][68];
    const int t = threadIdx.x;
    const float* src = (blockIdx.z == 0) ? src0 : src1;
    u16* d0 = dst + (size_t)blockIdx.z * 1024 * 1024;
    const int n0 = blockIdx.x * 64, k0 = blockIdx.y * 64;
    const int kl = t >> 4, nl = (t & 15) * 4;
#pragma unroll
    for (int p = 0; p < 4; ++p) {
        float4 v = *(const float4*)(src + (size_t)(k0 + kl + p * 16) * ld + n0 + nl);
        tile[kl + p * 16][nl + 0] = v.x;
        tile[kl + p * 16][nl + 1] = v.y;
        tile[kl + p * 16][nl + 2] = v.z;
        tile[kl + p * 16][nl + 3] = v.w;
    }
    __syncthreads();
    const int nl2 = t >> 2, kc = (t & 3) * 16;
    __align__(16) u16 tmp[16];
#pragma unroll
    for (int j = 0; j < 16; ++j) tmp[j] = f2bf(tile[kc + j][nl2]);
    u16* d = d0 + (size_t)(n0 + nl2) * 1024 + k0 + kc;
    ((uint4*)d)[0] = ((const uint4*)tmp)[0];
    ((uint4*)d)[1] = ((const uint4*)tmp)[1];
}

// -------- V transpose (bf16): per (b,h) [1024 j][64 d] -> [64 d][1024 j] --------
__global__ __launch_bounds__(256) void transpose_v(const u16* __restrict__ V,
                                                   u16* __restrict__ Vt) {
    __shared__ u16 tile[64][72];
    const int t = threadIdx.x;
    const int j0 = blockIdx.x * 64;
    const int bh = blockIdx.y;
    const u16* src = V + (size_t)bh * 65536;
    const int jl = t >> 4, dl = (t & 15) * 4;
#pragma unroll
    for (int p = 0; p < 4; ++p) {
        ushort4 v = *(const ushort4*)(src + (size_t)(j0 + jl + p * 16) * 64 + dl);
        *(ushort4*)&tile[jl + p * 16][dl] = v;
    }
    __syncthreads();
    const int dl2 = t >> 2, jc = (t & 3) * 16;
    __align__(16) u16 tmp[16];
#pragma unroll
    for (int j = 0; j < 16; ++j) tmp[j] = tile[jc + j][dl2];
    u16* d = Vt + (size_t)bh * 65536 + (size_t)dl2 * 1024 + j0 + jc;
    ((uint4*)d)[0] = ((const uint4*)tmp)[0];
    ((uint4*)d)[1] = ((const uint4*)tmp)[1];
}

// ---------------- GEMM1: qkv = xn @ Wqkv^T, BM=256 x BN=192, grid 16x16=256 ----------
// Exactly 1 block/CU (was 192 blocks = 64 idle CUs). WM=4/WN=2: wave tile 64x96,
// MQ=2, NQ=3. B staged as one full-tile unit (3 gloads); A in pow2 halves.
// Stage-write rule: target regions last ds_read in phase <= p-2 (ledger verified).
__global__ __launch_bounds__(512, 2) void gemm1k(const u16* __restrict__ A,
                                                 const u16* __restrict__ B,
                                                 u16* __restrict__ Qb, u16* __restrict__ Kb,
                                                 u16* __restrict__ Vb) {
    constexpr int MQ = 2, NQ = 3, HA = 32, HB = 48, TM = 64, TN = 96;
    constexpr int CHA = 1024, CHBF = 1536;  // chunks per A half / B full tile
    constexpr int NI = 8;

    __shared__ __align__(16) u16 As[2 * 2 * CHA * 8];   // 64 KB
    __shared__ __align__(16) u16 Bs[2 * CHBF * 8];      // 48 KB

    const int tid = threadIdx.x, lane = tid & 63;
    const int wave = tid >> 6;
    const int wm = wave >> 1, wn = wave & 1;
    const int lr = lane & 15, cg = lane >> 4;

    const int bid = blockIdx.x;                    // nwg = 256
    const int bid2 = (bid & 7) * 32 + (bid >> 3);  // XCD-aware bijective swizzle
    const int bxi = bid2 & 15, byi = bid2 >> 4;
    const int m0 = byi * 256, n0 = bxi * 192;

    const u16* __restrict__ Ag = A + (size_t)m0 * 1024;
    const u16* __restrict__ Bg = B + (size_t)n0 * 1024;

    f32x4 acc[2 * MQ][2 * NQ] = {};

#define STG_A(b, h, t)                                                              \
    do {                                                                            \
        _Pragma("unroll") for (int u = 0; u < 2; ++u) {                             \
            const int idx = u * 512 + tid;                                          \
            const int loc = idx >> 3, pp = idx & 7;                                 \
            const int row = (loc & 127) | ((h)*128);                                \
            gload_lds16(Ag + (size_t)row * 1024 + (t)*64 + ((pp ^ (row & 7)) << 3), \
                        &As[(((b)*2 + (h)) * CHA + idx) * 8]);                      \
        }                                                                           \
    } while (0)
#define STG_B(b, t)                                                                 \
    do {                                                                            \
        _Pragma("unroll") for (int u = 0; u < 3; ++u) {                             \
            const int idx = u * 512 + tid;                                          \
            const int row = idx >> 3, pp = idx & 7;                                 \
            gload_lds16(Bg + (size_t)row * 1024 + (t)*64 + ((pp ^ (row & 7)) << 3), \
                        &Bs[((b)*CHBF + idx) * 8]);                                 \
        }                                                                           \
    } while (0)

// A half h holds global rows h*128..h*128+127 linearly; wave row = wm*64+lm*32+mf*16+lr
// -> half = lm' where global row = wm*64+lm*32+... < 256: half = (row>=128), pos = row&127.
#define LDA(bb, lm, dst)                                                            \
    _Pragma("unroll") for (int mf = 0; mf < MQ; ++mf)                               \
        _Pragma("unroll") for (int ks = 0; ks < 2; ++ks) {                          \
            const int grow = wm * 64 + (lm)*32 + mf * 16 + lr;                      \
            dst[mf][ks] = *(const s16x8*)&As[((((bb)*2 + (grow >> 7)) * CHA) +      \
                                              (grow & 127) * 8 +                    \
                                              ((cg + ks * 4) ^ (lr & 7))) * 8];     \
        }

#define LDB(bb, ln, dst)                                                            \
    _Pragma("unroll") for (int nf = 0; nf < NQ; ++nf)                               \
        _Pragma("unroll") for (int ks = 0; ks < 2; ++ks) {                          \
            const int rr = wn * TN + (ln)*HB + nf * 16 + lr;                        \
            dst[nf][ks] = *(const s16x8*)&Bs[((bb)*CHBF + rr * 8 +                  \
                                              ((cg + ks * 4) ^ (lr & 7))) * 8];     \
        }

#define MM(lm, ln, A_, B_)                                                          \
    __builtin_amdgcn_s_setprio(1);                                                  \
    _Pragma("unroll") for (int mf = 0; mf < MQ; ++mf)                               \
        _Pragma("unroll") for (int nf = 0; nf < NQ; ++nf)                           \
            _Pragma("unroll") for (int ks = 0; ks < 2; ++ks)                        \
                acc[(lm)*MQ + mf][(ln)*NQ + nf] = mfma16(                           \
                    A_[mf][ks], B_[nf][ks], acc[(lm)*MQ + mf][(ln)*NQ + nf]);       \
    __builtin_amdgcn_s_setprio(0);

#define BAR() asm volatile("s_barrier" ::: "memory")

    // prologue: t0 fully (A0,A1,B = 7 loads) + t1 partial (A0,B = 5)
    STG_A(0, 0, 0);
    STG_A(0, 1, 0);
    STG_B(0, 0);
    STG_A(1, 0, 1);
    STG_B(1, 1);
    vmwait<5>();
    BAR();

    s16x8 va[MQ][2];
    s16x8 vb0[NQ][2], vb1[NQ][2];

#pragma unroll 1
    for (int i = 0; i < NI - 1; ++i) {
        const int t1 = 2 * i + 1, t2 = 2 * i + 2, t3 = 2 * i + 3;
        // ---- K-tile in buf0 ----
        LDA(0, 0, va); LDB(0, 0, vb0); STG_A(1, 1, t1); BAR(); MM(0, 0, va, vb0);
        LDB(0, 1, vb1);                                 BAR(); MM(0, 1, va, vb1);
        LDA(0, 1, va);                 STG_A(0, 0, t2); BAR(); MM(1, 0, va, vb0);
        STG_B(0, t2); vmwait<5>();                      BAR(); MM(1, 1, va, vb1);
        // ---- K-tile in buf1 ----
        LDA(1, 0, va); LDB(1, 0, vb0); STG_A(0, 1, t2); BAR(); MM(0, 0, va, vb0);
        LDB(1, 1, vb1);                                 BAR(); MM(0, 1, va, vb1);
        LDA(1, 1, va);                 STG_A(1, 0, t3); BAR(); MM(1, 0, va, vb0);
        STG_B(1, t3); vmwait<5>();                      BAR(); MM(1, 1, va, vb1);
    }
    // peeled last iteration (t14 in buf0, t15 in buf1)
    LDA(0, 0, va); LDB(0, 0, vb0); STG_A(1, 1, 15); BAR(); MM(0, 0, va, vb0);
    LDB(0, 1, vb1);                                 BAR(); MM(0, 1, va, vb1);
    LDA(0, 1, va);                                  BAR(); MM(1, 0, va, vb0);
    vmwait<0>();                                    BAR(); MM(1, 1, va, vb1);
    LDA(1, 0, va); LDB(1, 0, vb0); MM(0, 0, va, vb0);
    LDB(1, 1, vb1);                MM(0, 1, va, vb1);
    LDA(1, 1, va);                 MM(1, 0, va, vb0);
    MM(1, 1, va, vb1);

#undef STG_A
#undef STG_B
#undef LDA
#undef LDB
#undef MM
#undef BAR

#pragma unroll
    for (int am = 0; am < 2 * MQ; ++am) {
        const int lm = am / MQ, mf = am % MQ;
        const int rowb = m0 + wm * TM + lm * HA + mf * 16 + cg * 4;
#pragma unroll
        for (int an = 0; an < 2 * NQ; ++an) {
            const int ln = an / NQ, nf = an % NQ;
            const int col = n0 + wn * TN + ln * HB + nf * 16 + lr;
            const int which = col >> 10, hd = col & 1023;
            const int h = hd >> 6, dd = hd & 63;
            u16* dst = (which == 0) ? Qb : (which == 1) ? Kb : Vb;
            // Q pre-scaled by SCALE*log2(e) so softmax uses raw v_exp_f32
            const float sc = (which == 0) ? 0.18033688011112042f : 1.0f;
#pragma unroll
            for (int r = 0; r < 4; ++r) {
                const int tk = rowb + r;
                const int bb2 = tk >> 10, ii = tk & 1023;
                dst[(size_t)(((bb2 << 4) + h) * 1024 + ii) * 64 + dd] =
                    f2bf(acc[am][an][r] * sc);
            }
        }
    }
}

// ---------------- GEMM2 (round-6 structure, unchanged): out = xo @ Wout^T ------------
template <int BN, int WM, int EPI>
__global__ __launch_bounds__(512, 2) void gemm8(const u16* __restrict__ A,
                                                const u16* __restrict__ B,
                                                u16* __restrict__ Qb, u16* __restrict__ Kb,
                                                u16* __restrict__ Vb,
                                                const float* __restrict__ bx,
                                                const float* __restrict__ by,
                                                float* __restrict__ out, int NBX) {
    constexpr int BM = 256, WN = 8 / WM;
    constexpr int TM = BM / WM, TN = BN / WN;
    constexpr int MQ = TM / 32, NQ = TN / 32;
    constexpr int HA = TM / 2, HB = TN / 2;
    constexpr int CHA = 1024;
    constexpr int CHB = BN * 4;
    constexpr int GA = 2, GB = CHB / 512;
    constexpr int NI = 8;

    __shared__ __align__(16) u16 As[2 * 2 * CHA * 8];
    __shared__ __align__(16) u16 Bs[2 * 2 * CHB * 8];

    const int tid = threadIdx.x, lane = tid & 63;
    const int wave = tid >> 6;
    const int wm = wave / WN, wn = wave % WN;
    const int lr = lane & 15, cg = lane >> 4;

    const int nwg = NBX * 16;
    const int bid = blockIdx.x;
    const int bid2 = (bid & 7) * (nwg >> 3) + (bid >> 3);
    const int bxi = bid2 % NBX, byi = bid2 / NBX;
    const int m0 = byi * 256, n0 = bxi * BN;

    const u16* __restrict__ Ag = A + (size_t)m0 * 1024;
    const u16* __restrict__ Bg = B + (size_t)n0 * 1024;

    f32x4 acc[2 * MQ][2 * NQ] = {};

#define STG_A(b, h, t)                                                              \
    do {                                                                            \
        _Pragma("unroll") for (int u = 0; u < GA; ++u) {                            \
            const int idx = u * 512 + tid;                                          \
            const int loc = idx >> 3, pp = idx & 7;                                 \
            const int row = (loc & (HA - 1)) | ((h)*HA) | ((loc / HA) * 2 * HA);    \
            gload_lds16(Ag + (size_t)row * 1024 + (t)*64 + ((pp ^ (row & 7)) << 3), \
                        &As[(((b)*2 + (h)) * CHA + idx) * 8]);                      \
        }                                                                           \
    } while (0)
#define STG_B(b, h, t)                                                              \
    do {                                                                            \
        _Pragma("unroll") for (int u = 0; u < GB; ++u) {                            \
            const int idx = u * 512 + tid;                                          \
            const int loc = idx >> 3, pp = idx & 7;                                 \
            const int row = (loc & (HB - 1)) | ((h)*HB) | ((loc / HB) * 2 * HB);    \
            gload_lds16(Bg + (size_t)row * 1024 + (t)*64 + ((pp ^ (row & 7)) << 3), \
                        &Bs[(((b)*2 + (h)) * CHB + idx) * 8]);                      \
        }                                                                           \
    } while (0)

#define LDA(bb, lm, dst)                                                            \
    _Pragma("unroll") for (int mf = 0; mf < MQ; ++mf)                               \
        _Pragma("unroll") for (int ks = 0; ks < 2; ++ks)                            \
            dst[mf][ks] = *(const s16x8*)&As[((((bb)*2 + (lm)) * CHA) +             \
                                              (mf * 16 + lr + wm * HA) * 8 +        \
                                              ((cg + ks * 4) ^ (lr & 7))) * 8];

#define LDB(bb, ln, dst)                                                            \
    _Pragma("unroll") for (int nf = 0; nf < NQ; ++nf)                               \
        _Pragma("unroll") for (int ks = 0; ks < 2; ++ks)                            \
            dst[nf][ks] = *(const s16x8*)&Bs[((((bb)*2 + (ln)) * CHB) +             \
                                              (nf * 16 + lr + wn * HB) * 8 +        \
                                              ((cg + ks * 4) ^ (lr & 7))) * 8];

#define MM(lm, ln, A_, B_)                                                          \
    __builtin_amdgcn_s_setprio(1);                                                  \
    _Pragma("unroll") for (int mf = 0; mf < MQ; ++mf)                               \
        _Pragma("unroll") for (int nf = 0; nf < NQ; ++nf)                           \
            _Pragma("unroll") for (int ks = 0; ks < 2; ++ks)                        \
                acc[(lm)*MQ + mf][(ln)*NQ + nf] = mfma16(                           \
                    A_[mf][ks], B_[nf][ks], acc[(lm)*MQ + mf][(ln)*NQ + nf]);       \
    __builtin_amdgcn_s_setprio(0);

#define BAR() asm volatile("s_barrier" ::: "memory")

    STG_A(0, 0, 0);
    STG_A(0, 1, 0);
    STG_B(0, 0, 0);
    STG_B(0, 1, 0);
    STG_A(1, 0, 1);
    STG_B(1, 0, 1);
    vmwait<GA + GB>();
    BAR();

    s16x8 va[MQ][2];
    s16x8 vb0[NQ][2], vb1[NQ][2];

#pragma unroll 1
    for (int i = 0; i < NI - 1; ++i) {
        const int t1 = 2 * i + 1, t2 = 2 * i + 2, t3 = 2 * i + 3;
        LDA(0, 0, va); LDB(0, 0, vb0); STG_A(1, 1, t1); BAR(); MM(0, 0, va, vb0);
        LDB(0, 1, vb1);                STG_B(1, 1, t1); BAR(); MM(0, 1, va, vb1);
        LDA(0, 1, va);                 STG_A(0, 0, t2); BAR(); MM(1, 0, va, vb0);
        STG_B(0, 0, t2); vmwait<GA + GB>();             BAR(); MM(1, 1, va, vb1);
        LDA(1, 0, va); LDB(1, 0, vb0); STG_A(0, 1, t2); BAR(); MM(0, 0, va, vb0);
        LDB(1, 1, vb1);                STG_B(0, 1, t2); BAR(); MM(0, 1, va, vb1);
        LDA(1, 1, va);                 STG_A(1, 0, t3); BAR(); MM(1, 0, va, vb0);
        STG_B(1, 0, t3); vmwait<GA + GB>();             BAR(); MM(1, 1, va, vb1);
    }
    LDA(0, 0, va); LDB(0, 0, vb0); STG_A(1, 1, 15); BAR(); MM(0, 0, va, vb0);
    LDB(0, 1, vb1);                STG_B(1, 1, 15); BAR(); MM(0, 1, va, vb1);
    LDA(0, 1, va);                                  BAR(); MM(1, 0, va, vb0);
    vmwait<0>();                                    BAR(); MM(1, 1, va, vb1);
    LDA(1, 0, va); LDB(1, 0, vb0); MM(0, 0, va, vb0);
    LDB(1, 1, vb1);                MM(0, 1, va, vb1);
    LDA(1, 1, va);                 MM(1, 0, va, vb0);
    MM(1, 1, va, vb1);

#undef STG_A
#undef STG_B
#undef LDA
#undef LDB
#undef MM
#undef BAR

#pragma unroll
    for (int am = 0; am < 2 * MQ; ++am) {
        const int lm = am / MQ, mf = am % MQ;
        const int rowb = m0 + wm * TM + lm * HA + mf * 16 + cg * 4;
#pragma unroll
        for (int an = 0; an < 2 * NQ; ++an) {
            const int ln = an / NQ, nf = an % NQ;
            const int col = n0 + wn * TN + ln * HB + nf * 16 + lr;
            if (EPI == 0) {
                const int which = col >> 10, hd = col & 1023;
                const int h = hd >> 6, dd = hd & 63;
                u16* dst = (which == 0) ? Qb : (which == 1) ? Kb : Vb;
                const float sc = (which == 0) ? 0.18033688011112042f : 1.0f;
#pragma unroll
                for (int r = 0; r < 4; ++r) {
                    const int tk = rowb + r;
                    const int bb2 = tk >> 10, ii = tk & 1023;
                    dst[(size_t)(((bb2 << 4) + h) * 1024 + ii) * 64 + dd] =
                        f2bf(acc[am][an][r] * sc);
                }
            } else {
                float bias;
                float* ob;
                if (col < 1024) { bias = bx[col]; ob = out + col; }
                else { bias = by[col - 1024]; ob = out + 4194304 + (col - 1024); }
#pragma unroll
                for (int r = 0; r < 4; ++r)
                    ob[(size_t)(rowb + r) * 1024] = acc[am][an][r] + bias;
            }
        }
    }
}

// ---------------- Flash attention v6 (round-9, unchanged): 3-buffer ring -------------
__global__ __launch_bounds__(256) void attn_kernel(const u16* __restrict__ Q,
                                                   const u16* __restrict__ Kg,
                                                   const u16* __restrict__ Vt,
                                                   u16* __restrict__ xo) {
    __shared__ __align__(16) u16 Ks[3][64 * 64];
    __shared__ __align__(16) u16 Vs[3][64 * 64];
    __shared__ __align__(16) u16 Ps[4][32 * 64];
    const int tid = threadIdx.x, lane = tid & 63, w = tid >> 6;
    const int bid = blockIdx.x;
    const int bh = (bid & 7) * 8 + ((bid >> 3) & 7);  // XCD-grouped heads
    const int qblk = bid >> 6;
    const u16* Qh = Q + (size_t)bh * 65536;
    const u16* Kh = Kg + (size_t)bh * 65536;
    const u16* Vh = Vt + (size_t)bh * 65536;
    const int lr = lane & 15, cg = lane >> 4;
    const int q0 = qblk * 128 + w * 32;
    u16* Pw = &Ps[w][0];

    s16x8 qf[2][2];
#pragma unroll
    for (int qg = 0; qg < 2; ++qg)
#pragma unroll
        for (int ks = 0; ks < 2; ++ks)
            qf[qg][ks] =
                *(const s16x8*)(Qh + (size_t)(q0 + qg * 16 + lr) * 64 + ks * 32 + cg * 8);

    f32x4 o[2][4] = {};
    float l_s[2] = {0.f, 0.f};
    float m_s[2] = {-3e38f, -3e38f};
    int ba[4];
#pragma unroll
    for (int r = 0; r < 4; ++r) ba[r] = (cg * 4 + r) * 4;

#define STAGEKV(bufi, kv0)                                                               \
    do {                                                                                 \
        _Pragma("unroll") for (int i = 0; i < 2; ++i) {                                  \
            int idx = i * 256 + tid;                                                     \
            int row = idx >> 3, p = idx & 7;                                             \
            gload_lds16(Kh + (size_t)((kv0) + row) * 64 + ((p ^ (row & 7)) << 3),        \
                        &Ks[bufi][idx * 8]);                                             \
            gload_lds16(Vh + (size_t)row * 1024 + (kv0) + ((p ^ (row & 7)) << 3),        \
                        &Vs[bufi][idx * 8]);                                             \
        }                                                                                \
    } while (0)

    STAGEKV(0, 0);
    STAGEKV(1, 64);

    int buf = 0, sbuf = 2;
    for (int t = 0; t < 16; ++t) {
        if (t == 15) { vmwait<0>(); } else { vmwait<4>(); }
        asm volatile("s_barrier" ::: "memory");
        if (t < 14) STAGEKV(sbuf, (t + 2) * 64);

        f32x4 s[2][4] = {};
#pragma unroll
        for (int fn = 0; fn < 4; ++fn) {
            const int r = fn * 16 + lr;
#pragma unroll
            for (int ks = 0; ks < 2; ++ks) {
                const int c = cg + ks * 4;
                s16x8 kf = *(const s16x8*)&Ks[buf][r * 64 + ((c ^ (r & 7)) << 3)];
                s[0][fn] = mfma16(kf, qf[0][ks], s[0][fn]);
                s[1][fn] = mfma16(kf, qf[1][ks], s[1][fn]);
            }
        }

#pragma unroll
        for (int qg = 0; qg < 2; ++qg) {
            float tm = -3e38f;
#pragma unroll
            for (int fn = 0; fn < 4; ++fn)
#pragma unroll
                for (int r = 0; r < 4; ++r) tm = fmaxf(tm, s[qg][fn][r]);
            tm = fmaxf(tm, __shfl_xor(tm, 16));
            tm = fmaxf(tm, __shfl_xor(tm, 32));
            if (!__all(tm <= m_s[qg] + 8.0f)) {
                const float mn = fmaxf(m_s[qg], tm);
                const float corr = exp2a(m_s[qg] - mn);
                m_s[qg] = mn;
                l_s[qg] *= corr;
                f32x4 corr_o;
#pragma unroll
                for (int r = 0; r < 4; ++r)
                    corr_o[r] = __builtin_bit_cast(
                        float,
                        __builtin_amdgcn_ds_bpermute(ba[r], __builtin_bit_cast(int, corr)));
#pragma unroll
                for (int fd = 0; fd < 4; ++fd) o[qg][fd] *= corr_o;
            }
            const float mn = m_s[qg];
            float rs = 0.f;
            const int prow = (qg * 16 + lr) * 64;
#pragma unroll
            for (int fn = 0; fn < 4; ++fn) {
                const float p0 = exp2a(s[qg][fn][0] - mn);
                const float p1 = exp2a(s[qg][fn][1] - mn);
                const float p2 = exp2a(s[qg][fn][2] - mn);
                const float p3 = exp2a(s[qg][fn][3] - mn);
                rs += (p0 + p1) + (p2 + p3);
                uint2 dd;
                dd.x = cvtpk(p0, p1);
                dd.y = cvtpk(p2, p3);
                *(uint2*)(Pw + prow + (((2 * fn + (cg >> 1)) ^ (lr & 7)) << 3) +
                          ((cg & 1) << 2)) = dd;
            }
            rs += __shfl_xor(rs, 16);
            rs += __shfl_xor(rs, 32);
            l_s[qg] += rs;
        }

        s16x8 pf[2][2];
#pragma unroll
        for (int qg = 0; qg < 2; ++qg)
#pragma unroll
            for (int ks = 0; ks < 2; ++ks)
                pf[qg][ks] = *(const s16x8*)(Pw + (qg * 16 + lr) * 64 +
                                             (((4 * ks + cg) ^ (lr & 7)) << 3));
#pragma unroll
        for (int fd = 0; fd < 4; ++fd) {
            const int rr = fd * 16 + lr;
#pragma unroll
            for (int ks = 0; ks < 2; ++ks) {
                const int c = cg + ks * 4;
                s16x8 vf = *(const s16x8*)&Vs[buf][rr * 64 + ((c ^ (rr & 7)) << 3)];
                o[0][fd] = mfma16(pf[0][ks], vf, o[0][fd]);
                o[1][fd] = mfma16(pf[1][ks], vf, o[1][fd]);
            }
        }
        buf = (buf == 2) ? 0 : buf + 1;
        sbuf = (sbuf == 2) ? 0 : sbuf + 1;
    }
#undef STAGEKV

    const int b = bh >> 4, h = bh & 15;
#pragma unroll
    for (int qg = 0; qg < 2; ++qg) {
        f32x4 inv;
#pragma unroll
        for (int r = 0; r < 4; ++r) {
            const float lq = __builtin_bit_cast(
                float, __builtin_amdgcn_ds_bpermute(ba[r], __builtin_bit_cast(int, l_s[qg])));
            inv[r] = 1.0f / lq;
        }
#pragma unroll
        for (int r = 0; r < 4; ++r) {
            const int qrow = q0 + qg * 16 + cg * 4 + r;
#pragma unroll
            for (int fd = 0; fd < 4; ++fd)
                xo[(size_t)(b * 1024 + qrow) * 1024 + h * 64 + fd * 16 + lr] =
                    f2bf(o[qg][fd][r] * inv[r]);
        }
    }
}

extern "C" void kernel_launch(void* const* d_in, const int* in_sizes, int n_in,
                              void* d_out, int out_size, void* d_ws, size_t ws_size,
                              hipStream_t stream) {
    const float* x = (const float*)d_in[0];
    const float* gx = (const float*)d_in[2];
    const float* bxv = (const float*)d_in[3];
    const float* Wqkv = (const float*)d_in[6];
    const float* Woutx = (const float*)d_in[8];
    const float* boutx = (const float*)d_in[9];
    const float* Wouty = (const float*)d_in[10];
    const float* bouty = (const float*)d_in[11];
    float* out = (float*)d_out;

    u16* ws = (u16*)d_ws;
    u16* xn = ws;                           // 4096*1024
    u16* wqkv_t = xn + 4096 * 1024;         // 3072*1024
    u16* wout_t = wqkv_t + 3072 * 1024;     // 2048*1024
    u16* Qb = wout_t + 2048 * 1024;         // 64*1024*64
    u16* Kb = Qb + 64 * 1024 * 64;
    u16* Vb = Kb + 64 * 1024 * 64;
    u16* Vtb = Vb + 64 * 1024 * 64;
    u16* xob = Vtb + 64 * 1024 * 64;        // 4096*1024

    ln_kernel<<<4096, 256, 0, stream>>>(x, gx, bxv, xn);
    transpose_w<<<dim3(48, 16, 1), 256, 0, stream>>>(Wqkv, nullptr, wqkv_t, 3072);
    transpose_w<<<dim3(16, 16, 2), 256, 0, stream>>>(Woutx, Wouty, wout_t, 1024);
    gemm1k<<<256, 512, 0, stream>>>(xn, wqkv_t, Qb, Kb, Vb);
    transpose_v<<<dim3(16, 64), 256, 0, stream>>>(Vb, Vtb);
    attn_kernel<<<512, 256, 0, stream>>>(Qb, Kb, Vtb, xob);
    gemm8<128, 4, 1><<<256, 512, 0, stream>>>(xob, wout_t, nullptr, nullptr, nullptr,
                                              boutx, bouty, out, 16);
}

// Round 14
// 106.111 us; speedup vs baseline: 1.0003x; 1.0003x over previous
//
#include <hip/hip_runtime.h>

typedef __attribute__((ext_vector_type(8))) short s16x8;
typedef __attribute__((ext_vector_type(4))) float f32x4;
typedef unsigned short u16;

#define DEV __device__ __forceinline__

DEV u16 f2bf(float f) {
    unsigned u = __builtin_bit_cast(unsigned, f);
    unsigned r = u + 0x7fffu + ((u >> 16) & 1u);
    return (u16)(r >> 16);
}

DEV float exp2a(float x) {
    float r;
    asm("v_exp_f32 %0, %1" : "=v"(r) : "v"(x));
    return r;
}

DEV unsigned cvtpk(float lo, float hi) {
    unsigned r;
    asm("v_cvt_pk_bf16_f32 %0, %1, %2" : "=v"(r) : "v"(lo), "v"(hi));
    return r;
}

DEV void gload_lds16(const void* g, void* l) {
    __builtin_amdgcn_global_load_lds(
        (const __attribute__((address_space(1))) unsigned int*)g,
        (__attribute__((address_space(3))) unsigned int*)l, 16, 0, 0);
}

DEV f32x4 mfma16(s16x8 a, s16x8 b, f32x4 c) {
    return __builtin_amdgcn_mfma_f32_16x16x32_bf16(a, b, c, 0, 0, 0);
}

template <int N>
DEV void vmwait() {
    asm volatile("s_waitcnt vmcnt(%0)" ::"n"(N) : "memory");
}

// ---------------- LayerNorm: f32 in -> bf16 out, one block per row ----------------
__global__ __launch_bounds__(256) void ln_kernel(const float* __restrict__ x,
                                                 const float* __restrict__ g,
                                                 const float* __restrict__ b,
                                                 u16* __restrict__ xn) {
    const int row = blockIdx.x, t = threadIdx.x;
    const float4 v = *(const float4*)(x + (size_t)row * 1024 + t * 4);
    float s1 = v.x + v.y + v.z + v.w;
    float s2 = v.x * v.x + v.y * v.y + v.z * v.z + v.w * v.w;
#pragma unroll
    for (int d = 1; d < 64; d <<= 1) {
        s1 += __shfl_xor(s1, d);
        s2 += __shfl_xor(s2, d);
    }
    __shared__ float red[8];
    if ((t & 63) == 0) { red[(t >> 6) * 2] = s1; red[(t >> 6) * 2 + 1] = s2; }
    __syncthreads();
    s1 = red[0] + red[2] + red[4] + red[6];
    s2 = red[1] + red[3] + red[5] + red[7];
    const float mu = s1 * (1.0f / 1024.0f);
    const float var = s2 * (1.0f / 1024.0f) - mu * mu;
    const float rs = rsqrtf(var + 1e-5f);
    const float4 gv = *(const float4*)(g + t * 4);
    const float4 bv = *(const float4*)(b + t * 4);
    ushort4 o;
    o.x = f2bf((v.x - mu) * rs * gv.x + bv.x);
    o.y = f2bf((v.y - mu) * rs * gv.y + bv.y);
    o.z = f2bf((v.z - mu) * rs * gv.z + bv.z);
    o.w = f2bf((v.w - mu) * rs * gv.w + bv.w);
    *(ushort4*)(xn + (size_t)row * 1024 + t * 4) = o;
}

// -------- Weight transpose + cast: src f32 [1024 K][ld N] -> dst bf16 [N][1024] --------
__global__ __launch_bounds__(256) void transpose_w(const float* __restrict__ src0,
                                                   const float* __restrict__ src1,
                                                   u16* __restrict__ dst, int ld) {
    __shared__ float tile[64][68];
    const int t = threadIdx.x;
    const float* src = (blockIdx.z == 0) ? src0 : src1;
    u16* d0 = dst + (size_t)blockIdx.z * 1024 * 1024;
    const int n0 = blockIdx.x * 64, k0 = blockIdx.y * 64;
    const int kl = t >> 4, nl = (t & 15) * 4;
#pragma unroll
    for (int p = 0; p < 4; ++p) {
        float4 v = *(const float4*)(src + (size_t)(k0 + kl + p * 16) * ld + n0 + nl);
        tile[kl + p * 16][nl + 0] = v.x;
        tile[kl + p * 16][nl + 1] = v.y;
        tile[kl + p * 16][nl + 2] = v.z;
        tile[kl + p * 16][nl + 3] = v.w;
    }
    __syncthreads();
    const int nl2 = t >> 2, kc = (t & 3) * 16;
    __align__(16) u16 tmp[16];
#pragma unroll
    for (int j = 0; j < 16; ++j) tmp[j] = f2bf(tile[kc + j][nl2]);
    u16* d = d0 + (size_t)(n0 + nl2) * 1024 + k0 + kc;
    ((uint4*)d)[0] = ((const uint4*)tmp)[0];
    ((uint4*)d)[1] = ((const uint4*)tmp)[1];
}

// -------- V transpose (bf16): per (b,h) [1024 j][64 d] -> [64 d][1024 j] --------
__global__ __launch_bounds__(256) void transpose_v(const u16* __restrict__ V,
                                                   u16* __restrict__ Vt) {
    __shared__ u16 tile[64][72];
    const int t = threadIdx.x;
    const int j0 = blockIdx.x * 64;
    const int bh = blockIdx.y;
    const u16* src = V + (size_t)bh * 65536;
    const int jl = t >> 4, dl = (t & 15) * 4;
#pragma unroll
    for (int p = 0; p < 4; ++p) {
        ushort4 v = *(const ushort4*)(src + (size_t)(j0 + jl + p * 16) * 64 + dl);
        *(ushort4*)&tile[jl + p * 16][dl] = v;
    }
    __syncthreads();
    const int dl2 = t >> 2, jc = (t & 3) * 16;
    __align__(16) u16 tmp[16];
#pragma unroll
    for (int j = 0; j < 16; ++j) tmp[j] = tile[jc + j][dl2];
    u16* d = Vt + (size_t)bh * 65536 + (size_t)dl2 * 1024 + j0 + jc;
    ((uint4*)d)[0] = ((const uint4*)tmp)[0];
    ((uint4*)d)[1] = ((const uint4*)tmp)[1];
}

// ---------------- GEMM1: qkv = xn @ Wqkv^T, BM=256 x BN=192, grid 16x16=256 ----------
// Exactly 1 block/CU (was 192 blocks = 64 idle CUs). WM=4/WN=2: wave tile 64x96,
// MQ=2, NQ=3. B staged as one full-tile unit (3 gloads); A in pow2 halves.
// Stage-write rule: target regions last ds_read in phase <= p-2 (ledger verified).
__global__ __launch_bounds__(512, 2) void gemm1k(const u16* __restrict__ A,
                                                 const u16* __restrict__ B,
                                                 u16* __restrict__ Qb, u16* __restrict__ Kb,
                                                 u16* __restrict__ Vb) {
    constexpr int MQ = 2, NQ = 3, HA = 32, HB = 48, TM = 64, TN = 96;
    constexpr int CHA = 1024, CHBF = 1536;  // chunks per A half / B full tile
    constexpr int NI = 8;

    __shared__ __align__(16) u16 As[2 * 2 * CHA * 8];   // 64 KB
    __shared__ __align__(16) u16 Bs[2 * CHBF * 8];      // 48 KB

    const int tid = threadIdx.x, lane = tid & 63;
    const int wave = tid >> 6;
    const int wm = wave >> 1, wn = wave & 1;
    const int lr = lane & 15, cg = lane >> 4;

    const int bid = blockIdx.x;                    // nwg = 256
    const int bid2 = (bid & 7) * 32 + (bid >> 3);  // XCD-aware bijective swizzle
    const int bxi = bid2 & 15, byi = bid2 >> 4;
    const int m0 = byi * 256, n0 = bxi * 192;

    const u16* __restrict__ Ag = A + (size_t)m0 * 1024;
    const u16* __restrict__ Bg = B + (size_t)n0 * 1024;

    f32x4 acc[2 * MQ][2 * NQ] = {};

#define STG_A(b, h, t)                                                              \
    do {                                                                            \
        _Pragma("unroll") for (int u = 0; u < 2; ++u) {                             \
            const int idx = u * 512 + tid;                                          \
            const int loc = idx >> 3, pp = idx & 7;                                 \
            const int row = (loc & 127) | ((h)*128);                                \
            gload_lds16(Ag + (size_t)row * 1024 + (t)*64 + ((pp ^ (row & 7)) << 3), \
                        &As[(((b)*2 + (h)) * CHA + idx) * 8]);                      \
        }                                                                           \
    } while (0)
#define STG_B(b, t)                                                                 \
    do {                                                                            \
        _Pragma("unroll") for (int u = 0; u < 3; ++u) {                             \
            const int idx = u * 512 + tid;                                          \
            const int row = idx >> 3, pp = idx & 7;                                 \
            gload_lds16(Bg + (size_t)row * 1024 + (t)*64 + ((pp ^ (row & 7)) << 3), \
                        &Bs[((b)*CHBF + idx) * 8]);                                 \
        }                                                                           \
    } while (0)

// A half h holds global rows h*128..h*128+127 linearly; wave row = wm*64+lm*32+mf*16+lr
// -> half = lm' where global row = wm*64+lm*32+... < 256: half = (row>=128), pos = row&127.
#define LDA(bb, lm, dst)                                                            \
    _Pragma("unroll") for (int mf = 0; mf < MQ; ++mf)                               \
        _Pragma("unroll") for (int ks = 0; ks < 2; ++ks) {                          \
            const int grow = wm * 64 + (lm)*32 + mf * 16 + lr;                      \
            dst[mf][ks] = *(const s16x8*)&As[((((bb)*2 + (grow >> 7)) * CHA) +      \
                                              (grow & 127) * 8 +                    \
                                              ((cg + ks * 4) ^ (lr & 7))) * 8];     \
        }

#define LDB(bb, ln, dst)                                                            \
    _Pragma("unroll") for (int nf = 0; nf < NQ; ++nf)                               \
        _Pragma("unroll") for (int ks = 0; ks < 2; ++ks) {                          \
            const int rr = wn * TN + (ln)*HB + nf * 16 + lr;                        \
            dst[nf][ks] = *(const s16x8*)&Bs[((bb)*CHBF + rr * 8 +                  \
                                              ((cg + ks * 4) ^ (lr & 7))) * 8];     \
        }

#define MM(lm, ln, A_, B_)                                                          \
    __builtin_amdgcn_s_setprio(1);                                                  \
    _Pragma("unroll") for (int mf = 0; mf < MQ; ++mf)                               \
        _Pragma("unroll") for (int nf = 0; nf < NQ; ++nf)                           \
            _Pragma("unroll") for (int ks = 0; ks < 2; ++ks)                        \
                acc[(lm)*MQ + mf][(ln)*NQ + nf] = mfma16(                           \
                    A_[mf][ks], B_[nf][ks], acc[(lm)*MQ + mf][(ln)*NQ + nf]);       \
    __builtin_amdgcn_s_setprio(0);

#define BAR() asm volatile("s_barrier" ::: "memory")

    // prologue: t0 fully (A0,A1,B = 7 loads) + t1 partial (A0,B = 5)
    STG_A(0, 0, 0);
    STG_A(0, 1, 0);
    STG_B(0, 0);
    STG_A(1, 0, 1);
    STG_B(1, 1);
    vmwait<5>();
    BAR();

    s16x8 va[MQ][2];
    s16x8 vb0[NQ][2], vb1[NQ][2];

#pragma unroll 1
    for (int i = 0; i < NI - 1; ++i) {
        const int t1 = 2 * i + 1, t2 = 2 * i + 2, t3 = 2 * i + 3;
        // ---- K-tile in buf0 ----
        LDA(0, 0, va); LDB(0, 0, vb0); STG_A(1, 1, t1); BAR(); MM(0, 0, va, vb0);
        LDB(0, 1, vb1);                                 BAR(); MM(0, 1, va, vb1);
        LDA(0, 1, va);                 STG_A(0, 0, t2); BAR(); MM(1, 0, va, vb0);
        STG_B(0, t2); vmwait<5>();                      BAR(); MM(1, 1, va, vb1);
        // ---- K-tile in buf1 ----
        LDA(1, 0, va); LDB(1, 0, vb0); STG_A(0, 1, t2); BAR(); MM(0, 0, va, vb0);
        LDB(1, 1, vb1);                                 BAR(); MM(0, 1, va, vb1);
        LDA(1, 1, va);                 STG_A(1, 0, t3); BAR(); MM(1, 0, va, vb0);
        STG_B(1, t3); vmwait<5>();                      BAR(); MM(1, 1, va, vb1);
    }
    // peeled last iteration (t14 in buf0, t15 in buf1)
    LDA(0, 0, va); LDB(0, 0, vb0); STG_A(1, 1, 15); BAR(); MM(0, 0, va, vb0);
    LDB(0, 1, vb1);                                 BAR(); MM(0, 1, va, vb1);
    LDA(0, 1, va);                                  BAR(); MM(1, 0, va, vb0);
    vmwait<0>();                                    BAR(); MM(1, 1, va, vb1);
    LDA(1, 0, va); LDB(1, 0, vb0); MM(0, 0, va, vb0);
    LDB(1, 1, vb1);                MM(0, 1, va, vb1);
    LDA(1, 1, va);                 MM(1, 0, va, vb0);
    MM(1, 1, va, vb1);

#undef STG_A
#undef STG_B
#undef LDA
#undef LDB
#undef MM
#undef BAR

#pragma unroll
    for (int am = 0; am < 2 * MQ; ++am) {
        const int lm = am / MQ, mf = am % MQ;
        const int rowb = m0 + wm * TM + lm * HA + mf * 16 + cg * 4;
#pragma unroll
        for (int an = 0; an < 2 * NQ; ++an) {
            const int ln = an / NQ, nf = an % NQ;
            const int col = n0 + wn * TN + ln * HB + nf * 16 + lr;
            const int which = col >> 10, hd = col & 1023;
            const int h = hd >> 6, dd = hd & 63;
            u16* dst = (which == 0) ? Qb : (which == 1) ? Kb : Vb;
            // Q pre-scaled by SCALE*log2(e) so softmax uses raw v_exp_f32
            const float sc = (which == 0) ? 0.18033688011112042f : 1.0f;
#pragma unroll
            for (int r = 0; r < 4; ++r) {
                const int tk = rowb + r;
                const int bb2 = tk >> 10, ii = tk & 1023;
                dst[(size_t)(((bb2 << 4) + h) * 1024 + ii) * 64 + dd] =
                    f2bf(acc[am][an][r] * sc);
            }
        }
    }
}

// ---------------- GEMM2 (round-6 structure, unchanged): out = xo @ Wout^T ------------
template <int BN, int WM, int EPI>
__global__ __launch_bounds__(512, 2) void gemm8(const u16* __restrict__ A,
                                                const u16* __restrict__ B,
                                                u16* __restrict__ Qb, u16* __restrict__ Kb,
                                                u16* __restrict__ Vb,
                                                const float* __restrict__ bx,
                                                const float* __restrict__ by,
                                                float* __restrict__ out, int NBX) {
    constexpr int BM = 256, WN = 8 / WM;
    constexpr int TM = BM / WM, TN = BN / WN;
    constexpr int MQ = TM / 32, NQ = TN / 32;
    constexpr int HA = TM / 2, HB = TN / 2;
    constexpr int CHA = 1024;
    constexpr int CHB = BN * 4;
    constexpr int GA = 2, GB = CHB / 512;
    constexpr int NI = 8;

    __shared__ __align__(16) u16 As[2 * 2 * CHA * 8];
    __shared__ __align__(16) u16 Bs[2 * 2 * CHB * 8];

    const int tid = threadIdx.x, lane = tid & 63;
    const int wave = tid >> 6;
    const int wm = wave / WN, wn = wave % WN;
    const int lr = lane & 15, cg = lane >> 4;

    const int nwg = NBX * 16;
    const int bid = blockIdx.x;
    const int bid2 = (bid & 7) * (nwg >> 3) + (bid >> 3);
    const int bxi = bid2 % NBX, byi = bid2 / NBX;
    const int m0 = byi * 256, n0 = bxi * BN;

    const u16* __restrict__ Ag = A + (size_t)m0 * 1024;
    const u16* __restrict__ Bg = B + (size_t)n0 * 1024;

    f32x4 acc[2 * MQ][2 * NQ] = {};

#define STG_A(b, h, t)                                                              \
    do {                                                                            \
        _Pragma("unroll") for (int u = 0; u < GA; ++u) {                            \
            const int idx = u * 512 + tid;                                          \
            const int loc = idx >> 3, pp = idx & 7;                                 \
            const int row = (loc & (HA - 1)) | ((h)*HA) | ((loc / HA) * 2 * HA);    \
            gload_lds16(Ag + (size_t)row * 1024 + (t)*64 + ((pp ^ (row & 7)) << 3), \
                        &As[(((b)*2 + (h)) * CHA + idx) * 8]);                      \
        }                                                                           \
    } while (0)
#define STG_B(b, h, t)                                                              \
    do {                                                                            \
        _Pragma("unroll") for (int u = 0; u < GB; ++u) {                            \
            const int idx = u * 512 + tid;                                          \
            const int loc = idx >> 3, pp = idx & 7;                                 \
            const int row = (loc & (HB - 1)) | ((h)*HB) | ((loc / HB) * 2 * HB);    \
            gload_lds16(Bg + (size_t)row * 1024 + (t)*64 + ((pp ^ (row & 7)) << 3), \
                        &Bs[(((b)*2 + (h)) * CHB + idx) * 8]);                      \
        }                                                                           \
    } while (0)

#define LDA(bb, lm, dst)                                                            \
    _Pragma("unroll") for (int mf = 0; mf < MQ; ++mf)                               \
        _Pragma("unroll") for (int ks = 0; ks < 2; ++ks)                            \
            dst[mf][ks] = *(const s16x8*)&As[((((bb)*2 + (lm)) * CHA) +             \
                                              (mf * 16 + lr + wm * HA) * 8 +        \
                                              ((cg + ks * 4) ^ (lr & 7))) * 8];

#define LDB(bb, ln, dst)                                                            \
    _Pragma("unroll") for (int nf = 0; nf < NQ; ++nf)                               \
        _Pragma("unroll") for (int ks = 0; ks < 2; ++ks)                            \
            dst[nf][ks] = *(const s16x8*)&Bs[((((bb)*2 + (ln)) * CHB) +             \
                                              (nf * 16 + lr + wn * HB) * 8 +        \
                                              ((cg + ks * 4) ^ (lr & 7))) * 8];

#define MM(lm, ln, A_, B_)                                                          \
    __builtin_amdgcn_s_setprio(1);                                                  \
    _Pragma("unroll") for (int mf = 0; mf < MQ; ++mf)                               \
        _Pragma("unroll") for (int nf = 0; nf < NQ; ++nf)                           \
            _Pragma("unroll") for (int ks = 0; ks < 2; ++ks)                        \
                acc[(lm)*MQ + mf][(ln)*NQ + nf] = mfma16(                           \
                    A_[mf][ks], B_[nf][ks], acc[(lm)*MQ + mf][(ln)*NQ + nf]);       \
    __builtin_amdgcn_s_setprio(0);

#define BAR() asm volatile("s_barrier" ::: "memory")

    STG_A(0, 0, 0);
    STG_A(0, 1, 0);
    STG_B(0, 0, 0);
    STG_B(0, 1, 0);
    STG_A(1, 0, 1);
    STG_B(1, 0, 1);
    vmwait<GA + GB>();
    BAR();

    s16x8 va[MQ][2];
    s16x8 vb0[NQ][2], vb1[NQ][2];

#pragma unroll 1
    for (int i = 0; i < NI - 1; ++i) {
        const int t1 = 2 * i + 1, t2 = 2 * i + 2, t3 = 2 * i + 3;
        LDA(0, 0, va); LDB(0, 0, vb0); STG_A(1, 1, t1); BAR(); MM(0, 0, va, vb0);
        LDB(0, 1, vb1);                STG_B(1, 1, t1); BAR(); MM(0, 1, va, vb1);
        LDA(0, 1, va);                 STG_A(0, 0, t2); BAR(); MM(1, 0, va, vb0);
        STG_B(0, 0, t2); vmwait<GA + GB>();             BAR(); MM(1, 1, va, vb1);
        LDA(1, 0, va); LDB(1, 0, vb0); STG_A(0, 1, t2); BAR(); MM(0, 0, va, vb0);
        LDB(1, 1, vb1);                STG_B(0, 1, t2); BAR(); MM(0, 1, va, vb1);
        LDA(1, 1, va);                 STG_A(1, 0, t3); BAR(); MM(1, 0, va, vb0);
        STG_B(1, 0, t3); vmwait<GA + GB>();             BAR(); MM(1, 1, va, vb1);
    }
    LDA(0, 0, va); LDB(0, 0, vb0); STG_A(1, 1, 15); BAR(); MM(0, 0, va, vb0);
    LDB(0, 1, vb1);                STG_B(1, 1, 15); BAR(); MM(0, 1, va, vb1);
    LDA(0, 1, va);                                  BAR(); MM(1, 0, va, vb0);
    vmwait<0>();                                    BAR(); MM(1, 1, va, vb1);
    LDA(1, 0, va); LDB(1, 0, vb0); MM(0, 0, va, vb0);
    LDB(1, 1, vb1);                MM(0, 1, va, vb1);
    LDA(1, 1, va);                 MM(1, 0, va, vb0);
    MM(1, 1, va, vb1);

#undef STG_A
#undef STG_B
#undef LDA
#undef LDB
#undef MM
#undef BAR

#pragma unroll
    for (int am = 0; am < 2 * MQ; ++am) {
        const int lm = am / MQ, mf = am % MQ;
        const int rowb = m0 + wm * TM + lm * HA + mf * 16 + cg * 4;
#pragma unroll
        for (int an = 0; an < 2 * NQ; ++an) {
            const int ln = an / NQ, nf = an % NQ;
            const int col = n0 + wn * TN + ln * HB + nf * 16 + lr;
            if (EPI == 0) {
                const int which = col >> 10, hd = col & 1023;
                const int h = hd >> 6, dd = hd & 63;
                u16* dst = (which == 0) ? Qb : (which == 1) ? Kb : Vb;
                const float sc = (which == 0) ? 0.18033688011112042f : 1.0f;
#pragma unroll
                for (int r = 0; r < 4; ++r) {
                    const int tk = rowb + r;
                    const int bb2 = tk >> 10, ii = tk & 1023;
                    dst[(size_t)(((bb2 << 4) + h) * 1024 + ii) * 64 + dd] =
                        f2bf(acc[am][an][r] * sc);
                }
            } else {
                float bias;
                float* ob;
                if (col < 1024) { bias = bx[col]; ob = out + col; }
                else { bias = by[col - 1024]; ob = out + 4194304 + (col - 1024); }
#pragma unroll
                for (int r = 0; r < 4; ++r)
                    ob[(size_t)(rowb + r) * 1024] = acc[am][an][r] + bias;
            }
        }
    }
}

// ---------------- Flash attention v6 (round-9, unchanged): 3-buffer ring -------------
__global__ __launch_bounds__(256) void attn_kernel(const u16* __restrict__ Q,
                                                   const u16* __restrict__ Kg,
                                                   const u16* __restrict__ Vt,
                                                   u16* __restrict__ xo) {
    __shared__ __align__(16) u16 Ks[3][64 * 64];
    __shared__ __align__(16) u16 Vs[3][64 * 64];
    __shared__ __align__(16) u16 Ps[4][32 * 64];
    const int tid = threadIdx.x, lane = tid & 63, w = tid >> 6;
    const int bid = blockIdx.x;
    const int bh = (bid & 7) * 8 + ((bid >> 3) & 7);  // XCD-grouped heads
    const int qblk = bid >> 6;
    const u16* Qh = Q + (size_t)bh * 65536;
    const u16* Kh = Kg + (size_t)bh * 65536;
    const u16* Vh = Vt + (size_t)bh * 65536;
    const int lr = lane & 15, cg = lane >> 4;
    const int q0 = qblk * 128 + w * 32;
    u16* Pw = &Ps[w][0];

    s16x8 qf[2][2];
#pragma unroll
    for (int qg = 0; qg < 2; ++qg)
#pragma unroll
        for (int ks = 0; ks < 2; ++ks)
            qf[qg][ks] =
                *(const s16x8*)(Qh + (size_t)(q0 + qg * 16 + lr) * 64 + ks * 32 + cg * 8);

    f32x4 o[2][4] = {};
    float l_s[2] = {0.f, 0.f};
    float m_s[2] = {-3e38f, -3e38f};
    int ba[4];
#pragma unroll
    for (int r = 0; r < 4; ++r) ba[r] = (cg * 4 + r) * 4;

#define STAGEKV(bufi, kv0)                                                               \
    do {                                                                                 \
        _Pragma("unroll") for (int i = 0; i < 2; ++i) {                                  \
            int idx = i * 256 + tid;                                                     \
            int row = idx >> 3, p = idx & 7;                                             \
            gload_lds16(Kh + (size_t)((kv0) + row) * 64 + ((p ^ (row & 7)) << 3),        \
                        &Ks[bufi][idx * 8]);                                             \
            gload_lds16(Vh + (size_t)row * 1024 + (kv0) + ((p ^ (row & 7)) << 3),        \
                        &Vs[bufi][idx * 8]);                                             \
        }                                                                                \
    } while (0)

    STAGEKV(0, 0);
    STAGEKV(1, 64);

    int buf = 0, sbuf = 2;
    for (int t = 0; t < 16; ++t) {
        if (t == 15) { vmwait<0>(); } else { vmwait<4>(); }
        asm volatile("s_barrier" ::: "memory");
        if (t < 14) STAGEKV(sbuf, (t + 2) * 64);

        f32x4 s[2][4] = {};
#pragma unroll
        for (int fn = 0; fn < 4; ++fn) {
            const int r = fn * 16 + lr;
#pragma unroll
            for (int ks = 0; ks < 2; ++ks) {
                const int c = cg + ks * 4;
                s16x8 kf = *(const s16x8*)&Ks[buf][r * 64 + ((c ^ (r & 7)) << 3)];
                s[0][fn] = mfma16(kf, qf[0][ks], s[0][fn]);
                s[1][fn] = mfma16(kf, qf[1][ks], s[1][fn]);
            }
        }

#pragma unroll
        for (int qg = 0; qg < 2; ++qg) {
            float tm = -3e38f;
#pragma unroll
            for (int fn = 0; fn < 4; ++fn)
#pragma unroll
                for (int r = 0; r < 4; ++r) tm = fmaxf(tm, s[qg][fn][r]);
            tm = fmaxf(tm, __shfl_xor(tm, 16));
            tm = fmaxf(tm, __shfl_xor(tm, 32));
            if (!__all(tm <= m_s[qg] + 8.0f)) {
                const float mn = fmaxf(m_s[qg], tm);
                const float corr = exp2a(m_s[qg] - mn);
                m_s[qg] = mn;
                l_s[qg] *= corr;
                f32x4 corr_o;
#pragma unroll
                for (int r = 0; r < 4; ++r)
                    corr_o[r] = __builtin_bit_cast(
                        float,
                        __builtin_amdgcn_ds_bpermute(ba[r], __builtin_bit_cast(int, corr)));
#pragma unroll
                for (int fd = 0; fd < 4; ++fd) o[qg][fd] *= corr_o;
            }
            const float mn = m_s[qg];
            float rs = 0.f;
            const int prow = (qg * 16 + lr) * 64;
#pragma unroll
            for (int fn = 0; fn < 4; ++fn) {
                const float p0 = exp2a(s[qg][fn][0] - mn);
                const float p1 = exp2a(s[qg][fn][1] - mn);
                const float p2 = exp2a(s[qg][fn][2] - mn);
                const float p3 = exp2a(s[qg][fn][3] - mn);
                rs += (p0 + p1) + (p2 + p3);
                uint2 dd;
                dd.x = cvtpk(p0, p1);
                dd.y = cvtpk(p2, p3);
                *(uint2*)(Pw + prow + (((2 * fn + (cg >> 1)) ^ (lr & 7)) << 3) +
                          ((cg & 1) << 2)) = dd;
            }
            rs += __shfl_xor(rs, 16);
            rs += __shfl_xor(rs, 32);
            l_s[qg] += rs;
        }

        s16x8 pf[2][2];
#pragma unroll
        for (int qg = 0; qg < 2; ++qg)
#pragma unroll
            for (int ks = 0; ks < 2; ++ks)
                pf[qg][ks] = *(const s16x8*)(Pw + (qg * 16 + lr) * 64 +
                                             (((4 * ks + cg) ^ (lr & 7)) << 3));
#pragma unroll
        for (int fd = 0; fd < 4; ++fd) {
            const int rr = fd * 16 + lr;
#pragma unroll
            for (int ks = 0; ks < 2; ++ks) {
                const int c = cg + ks * 4;
                s16x8 vf = *(const s16x8*)&Vs[buf][rr * 64 + ((c ^ (rr & 7)) << 3)];
                o[0][fd] = mfma16(pf[0][ks], vf, o[0][fd]);
                o[1][fd] = mfma16(pf[1][ks], vf, o[1][fd]);
            }
        }
        buf = (buf == 2) ? 0 : buf + 1;
        sbuf = (sbuf == 2) ? 0 : sbuf + 1;
    }
#undef STAGEKV

    const int b = bh >> 4, h = bh & 15;
#pragma unroll
    for (int qg = 0; qg < 2; ++qg) {
        f32x4 inv;
#pragma unroll
        for (int r = 0; r < 4; ++r) {
            const float lq = __builtin_bit_cast(
                float, __builtin_amdgcn_ds_bpermute(ba[r], __builtin_bit_cast(int, l_s[qg])));
            inv[r] = 1.0f / lq;
        }
#pragma unroll
        for (int r = 0; r < 4; ++r) {
            const int qrow = q0 + qg * 16 + cg * 4 + r;
#pragma unroll
            for (int fd = 0; fd < 4; ++fd)
                xo[(size_t)(b * 1024 + qrow) * 1024 + h * 64 + fd * 16 + lr] =
                    f2bf(o[qg][fd][r] * inv[r]);
        }
    }
}

extern "C" void kernel_launch(void* const* d_in, const int* in_sizes, int n_in,
                              void* d_out, int out_size, void* d_ws, size_t ws_size,
                              hipStream_t stream) {
    const float* x = (const float*)d_in[0];
    const float* gx = (const float*)d_in[2];
    const float* bxv = (const float*)d_in[3];
    const float* Wqkv = (const float*)d_in[6];
    const float* Woutx = (const float*)d_in[8];
    const float* boutx = (const float*)d_in[9];
    const float* Wouty = (const float*)d_in[10];
    const float* bouty = (const float*)d_in[11];
    float* out = (float*)d_out;

    u16* ws = (u16*)d_ws;
    u16* xn = ws;                           // 4096*1024
    u16* wqkv_t = xn + 4096 * 1024;         // 3072*1024
    u16* wout_t = wqkv_t + 3072 * 1024;     // 2048*1024
    u16* Qb = wout_t + 2048 * 1024;         // 64*1024*64
    u16* Kb = Qb + 64 * 1024 * 64;
    u16* Vb = Kb + 64 * 1024 * 64;
    u16* Vtb = Vb + 64 * 1024 * 64;
    u16* xob = Vtb + 64 * 1024 * 64;        // 4096*1024

    ln_kernel<<<4096, 256, 0, stream>>>(x, gx, bxv, xn);
    transpose_w<<<dim3(48, 16, 1), 256, 0, stream>>>(Wqkv, nullptr, wqkv_t, 3072);
    transpose_w<<<dim3(16, 16, 2), 256, 0, stream>>>(Woutx, Wouty, wout_t, 1024);
    gemm1k<<<256, 512, 0, stream>>>(xn, wqkv_t, Qb, Kb, Vb);
    transpose_v<<<dim3(16, 64), 256, 0, stream>>>(Vb, Vtb);
    attn_kernel<<<512, 256, 0, stream>>>(Qb, Kb, Vtb, xob);
    gemm8<128, 4, 1><<<256, 512, 0, stream>>>(xob, wout_t, nullptr, nullptr, nullptr,
                                              boutx, bouty, out, 16);
}

// Round 15
// 99.162 us; speedup vs baseline: 1.0704x; 1.0701x over previous
//
#include <hip/hip_runtime.h>

typedef __attribute__((ext_vector_type(8))) short s16x8;
typedef __attribute__((ext_vector_type(4))) float f32x4;
typedef unsigned short u16;

#define DEV __device__ __forceinline__

DEV u16 f2bf(float f) {
    unsigned u = __builtin_bit_cast(unsigned, f);
    unsigned r = u + 0x7fffu + ((u >> 16) & 1u);
    return (u16)(r >> 16);
}

DEV float exp2a(float x) {
    float r;
    asm("v_exp_f32 %0, %1" : "=v"(r) : "v"(x));
    return r;
}

DEV unsigned cvtpk(float lo, float hi) {
    unsigned r;
    asm("v_cvt_pk_bf16_f32 %0, %1, %2" : "=v"(r) : "v"(lo), "v"(hi));
    return r;
}

DEV void gload_lds16(const void* g, void* l) {
    __builtin_amdgcn_global_load_lds(
        (const __attribute__((address_space(1))) unsigned int*)g,
        (__attribute__((address_space(3))) unsigned int*)l, 16, 0, 0);
}

DEV f32x4 mfma16(s16x8 a, s16x8 b, f32x4 c) {
    return __builtin_amdgcn_mfma_f32_16x16x32_bf16(a, b, c, 0, 0, 0);
}

template <int N>
DEV void vmwait() {
    asm volatile("s_waitcnt vmcnt(%0)" ::"n"(N) : "memory");
}

// ---------------- prep: LN (blocks 0..4095) + Wqkv transpose (4096..4863)
//                  + Wout x/y transpose (4864..5375), one launch ----------------
__global__ __launch_bounds__(256) void prep_kernel(
    const float* __restrict__ x, const float* __restrict__ g,
    const float* __restrict__ b, u16* __restrict__ xn,
    const float* __restrict__ Wqkv, const float* __restrict__ Woutx,
    const float* __restrict__ Wouty, u16* __restrict__ wqkv_t,
    u16* __restrict__ wout_t) {
    __shared__ float tile[64][68];
    const int t = threadIdx.x;
    const int bid = blockIdx.x;

    if (bid < 4096) {
        // ---- LayerNorm row ----
        const int row = bid;
        const float4 v = *(const float4*)(x + (size_t)row * 1024 + t * 4);
        float s1 = v.x + v.y + v.z + v.w;
        float s2 = v.x * v.x + v.y * v.y + v.z * v.z + v.w * v.w;
#pragma unroll
        for (int d = 1; d < 64; d <<= 1) {
            s1 += __shfl_xor(s1, d);
            s2 += __shfl_xor(s2, d);
        }
        float* red = &tile[0][0];
        if ((t & 63) == 0) { red[(t >> 6) * 2] = s1; red[(t >> 6) * 2 + 1] = s2; }
        __syncthreads();
        s1 = red[0] + red[2] + red[4] + red[6];
        s2 = red[1] + red[3] + red[5] + red[7];
        const float mu = s1 * (1.0f / 1024.0f);
        const float var = s2 * (1.0f / 1024.0f) - mu * mu;
        const float rs = rsqrtf(var + 1e-5f);
        const float4 gv = *(const float4*)(g + t * 4);
        const float4 bv = *(const float4*)(b + t * 4);
        ushort4 o;
        o.x = f2bf((v.x - mu) * rs * gv.x + bv.x);
        o.y = f2bf((v.y - mu) * rs * gv.y + bv.y);
        o.z = f2bf((v.z - mu) * rs * gv.z + bv.z);
        o.w = f2bf((v.w - mu) * rs * gv.w + bv.w);
        *(ushort4*)(xn + (size_t)row * 1024 + t * 4) = o;
        return;
    }

    // ---- Weight transpose: src f32 [1024 K][ld N] -> dst bf16 [N][1024] ----
    const float* src;
    u16* d0;
    int ld, n0, k0;
    if (bid < 4096 + 768) {
        const int idx = bid - 4096;  // 48 x 16
        src = Wqkv; d0 = wqkv_t; ld = 3072;
        n0 = (idx % 48) * 64; k0 = (idx / 48) * 64;
    } else {
        const int idx = bid - 4096 - 768;  // 2 x 16 x 16
        const int z = idx >> 8, rem = idx & 255;
        src = (z == 0) ? Woutx : Wouty;
        d0 = wout_t + (size_t)z * 1024 * 1024; ld = 1024;
        n0 = (rem & 15) * 64; k0 = (rem >> 4) * 64;
    }
    const int kl = t >> 4, nl = (t & 15) * 4;
#pragma unroll
    for (int p = 0; p < 4; ++p) {
        float4 v = *(const float4*)(src + (size_t)(k0 + kl + p * 16) * ld + n0 + nl);
        tile[kl + p * 16][nl + 0] = v.x;
        tile[kl + p * 16][nl + 1] = v.y;
        tile[kl + p * 16][nl + 2] = v.z;
        tile[kl + p * 16][nl + 3] = v.w;
    }
    __syncthreads();
    const int nl2 = t >> 2, kc = (t & 3) * 16;
    __align__(16) u16 tmp[16];
#pragma unroll
    for (int j = 0; j < 16; ++j) tmp[j] = f2bf(tile[kc + j][nl2]);
    u16* d = d0 + (size_t)(n0 + nl2) * 1024 + k0 + kc;
    ((uint4*)d)[0] = ((const uint4*)tmp)[0];
    ((uint4*)d)[1] = ((const uint4*)tmp)[1];
}

// ---------------- GEMM1: qkv = xn @ Wqkv^T, BM=256 x BN=192, grid 16x16=256 ----------
// 1 block/CU. WM=4/WN=2: wave tile 64x96, MQ=2, NQ=3. V written DIRECTLY in
// transposed [64 d][1024 j] layout (packed ushort4) -> no transpose_v kernel.
__global__ __launch_bounds__(512, 2) void gemm1k(const u16* __restrict__ A,
                                                 const u16* __restrict__ B,
                                                 u16* __restrict__ Qb, u16* __restrict__ Kb,
                                                 u16* __restrict__ Vt) {
    constexpr int MQ = 2, NQ = 3, HA = 32, HB = 48, TM = 64, TN = 96;
    constexpr int CHA = 1024, CHBF = 1536;
    constexpr int NI = 8;

    __shared__ __align__(16) u16 As[2 * 2 * CHA * 8];   // 64 KB
    __shared__ __align__(16) u16 Bs[2 * CHBF * 8];      // 48 KB

    const int tid = threadIdx.x, lane = tid & 63;
    const int wave = tid >> 6;
    const int wm = wave >> 1, wn = wave & 1;
    const int lr = lane & 15, cg = lane >> 4;

    const int bid = blockIdx.x;                    // nwg = 256
    const int bid2 = (bid & 7) * 32 + (bid >> 3);  // XCD-aware bijective swizzle
    const int bxi = bid2 & 15, byi = bid2 >> 4;
    const int m0 = byi * 256, n0 = bxi * 192;

    const u16* __restrict__ Ag = A + (size_t)m0 * 1024;
    const u16* __restrict__ Bg = B + (size_t)n0 * 1024;

    f32x4 acc[2 * MQ][2 * NQ] = {};

#define STG_A(b, h, t)                                                              \
    do {                                                                            \
        _Pragma("unroll") for (int u = 0; u < 2; ++u) {                             \
            const int idx = u * 512 + tid;                                          \
            const int loc = idx >> 3, pp = idx & 7;                                 \
            const int row = (loc & 127) | ((h)*128);                                \
            gload_lds16(Ag + (size_t)row * 1024 + (t)*64 + ((pp ^ (row & 7)) << 3), \
                        &As[(((b)*2 + (h)) * CHA + idx) * 8]);                      \
        }                                                                           \
    } while (0)
#define STG_B(b, t)                                                                 \
    do {                                                                            \
        _Pragma("unroll") for (int u = 0; u < 3; ++u) {                             \
            const int idx = u * 512 + tid;                                          \
            const int row = idx >> 3, pp = idx & 7;                                 \
            gload_lds16(Bg + (size_t)row * 1024 + (t)*64 + ((pp ^ (row & 7)) << 3), \
                        &Bs[((b)*CHBF + idx) * 8]);                                 \
        }                                                                           \
    } while (0)

#define LDA(bb, lm, dst)                                                            \
    _Pragma("unroll") for (int mf = 0; mf < MQ; ++mf)                               \
        _Pragma("unroll") for (int ks = 0; ks < 2; ++ks) {                          \
            const int grow = wm * 64 + (lm)*32 + mf * 16 + lr;                      \
            dst[mf][ks] = *(const s16x8*)&As[((((bb)*2 + (grow >> 7)) * CHA) +      \
                                              (grow & 127) * 8 +                    \
                                              ((cg + ks * 4) ^ (lr & 7))) * 8];     \
        }

#define LDB(bb, ln, dst)                                                            \
    _Pragma("unroll") for (int nf = 0; nf < NQ; ++nf)                               \
        _Pragma("unroll") for (int ks = 0; ks < 2; ++ks) {                          \
            const int rr = wn * TN + (ln)*HB + nf * 16 + lr;                        \
            dst[nf][ks] = *(const s16x8*)&Bs[((bb)*CHBF + rr * 8 +                  \
                                              ((cg + ks * 4) ^ (lr & 7))) * 8];     \
        }

#define MM(lm, ln, A_, B_)                                                          \
    __builtin_amdgcn_s_setprio(1);                                                  \
    _Pragma("unroll") for (int mf = 0; mf < MQ; ++mf)                               \
        _Pragma("unroll") for (int nf = 0; nf < NQ; ++nf)                           \
            _Pragma("unroll") for (int ks = 0; ks < 2; ++ks)                        \
                acc[(lm)*MQ + mf][(ln)*NQ + nf] = mfma16(                           \
                    A_[mf][ks], B_[nf][ks], acc[(lm)*MQ + mf][(ln)*NQ + nf]);       \
    __builtin_amdgcn_s_setprio(0);

#define BAR() asm volatile("s_barrier" ::: "memory")

    STG_A(0, 0, 0);
    STG_A(0, 1, 0);
    STG_B(0, 0);
    STG_A(1, 0, 1);
    STG_B(1, 1);
    vmwait<5>();
    BAR();

    s16x8 va[MQ][2];
    s16x8 vb0[NQ][2], vb1[NQ][2];

#pragma unroll 1
    for (int i = 0; i < NI - 1; ++i) {
        const int t1 = 2 * i + 1, t2 = 2 * i + 2, t3 = 2 * i + 3;
        LDA(0, 0, va); LDB(0, 0, vb0); STG_A(1, 1, t1); BAR(); MM(0, 0, va, vb0);
        LDB(0, 1, vb1);                                 BAR(); MM(0, 1, va, vb1);
        LDA(0, 1, va);                 STG_A(0, 0, t2); BAR(); MM(1, 0, va, vb0);
        STG_B(0, t2); vmwait<5>();                      BAR(); MM(1, 1, va, vb1);
        LDA(1, 0, va); LDB(1, 0, vb0); STG_A(0, 1, t2); BAR(); MM(0, 0, va, vb0);
        LDB(1, 1, vb1);                                 BAR(); MM(0, 1, va, vb1);
        LDA(1, 1, va);                 STG_A(1, 0, t3); BAR(); MM(1, 0, va, vb0);
        STG_B(1, t3); vmwait<5>();                      BAR(); MM(1, 1, va, vb1);
    }
    LDA(0, 0, va); LDB(0, 0, vb0); STG_A(1, 1, 15); BAR(); MM(0, 0, va, vb0);
    LDB(0, 1, vb1);                                 BAR(); MM(0, 1, va, vb1);
    LDA(0, 1, va);                                  BAR(); MM(1, 0, va, vb0);
    vmwait<0>();                                    BAR(); MM(1, 1, va, vb1);
    LDA(1, 0, va); LDB(1, 0, vb0); MM(0, 0, va, vb0);
    LDB(1, 1, vb1);                MM(0, 1, va, vb1);
    LDA(1, 1, va);                 MM(1, 0, va, vb0);
    MM(1, 1, va, vb1);

#undef STG_A
#undef STG_B
#undef LDA
#undef LDB
#undef MM
#undef BAR

#pragma unroll
    for (int am = 0; am < 2 * MQ; ++am) {
        const int lm = am / MQ, mf = am % MQ;
        const int rowb = m0 + wm * TM + lm * HA + mf * 16 + cg * 4;
        const int bb2 = rowb >> 10, ii = rowb & 1023;
#pragma unroll
        for (int an = 0; an < 2 * NQ; ++an) {
            const int ln = an / NQ, nf = an % NQ;
            const int col = n0 + wn * TN + ln * HB + nf * 16 + lr;
            const int which = col >> 10, hd = col & 1023;
            const int h = hd >> 6, dd = hd & 63;
            if (which == 2) {
                // V: write transposed layout [bh][64 d][1024 j], packed 4 j's
                ushort4 pk;
                pk.x = f2bf(acc[am][an][0]);
                pk.y = f2bf(acc[am][an][1]);
                pk.z = f2bf(acc[am][an][2]);
                pk.w = f2bf(acc[am][an][3]);
                *(ushort4*)(Vt + (size_t)((bb2 << 4) + h) * 65536 + dd * 1024 + ii) = pk;
            } else {
                u16* dst = (which == 0) ? Qb : Kb;
                // Q pre-scaled by SCALE*log2(e) so softmax uses raw v_exp_f32
                const float sc = (which == 0) ? 0.18033688011112042f : 1.0f;
#pragma unroll
                for (int r = 0; r < 4; ++r)
                    dst[(size_t)(((bb2 << 4) + h) * 1024 + ii + r) * 64 + dd] =
                        f2bf(acc[am][an][r] * sc);
            }
        }
    }
}

// ---------------- GEMM2 (round-6 structure, unchanged): out = xo @ Wout^T ------------
template <int BN, int WM, int EPI>
__global__ __launch_bounds__(512, 2) void gemm8(const u16* __restrict__ A,
                                                const u16* __restrict__ B,
                                                u16* __restrict__ Qb, u16* __restrict__ Kb,
                                                u16* __restrict__ Vb,
                                                const float* __restrict__ bx,
                                                const float* __restrict__ by,
                                                float* __restrict__ out, int NBX) {
    constexpr int BM = 256, WN = 8 / WM;
    constexpr int TM = BM / WM, TN = BN / WN;
    constexpr int MQ = TM / 32, NQ = TN / 32;
    constexpr int HA = TM / 2, HB = TN / 2;
    constexpr int CHA = 1024;
    constexpr int CHB = BN * 4;
    constexpr int GA = 2, GB = CHB / 512;
    constexpr int NI = 8;

    __shared__ __align__(16) u16 As[2 * 2 * CHA * 8];
    __shared__ __align__(16) u16 Bs[2 * 2 * CHB * 8];

    const int tid = threadIdx.x, lane = tid & 63;
    const int wave = tid >> 6;
    const int wm = wave / WN, wn = wave % WN;
    const int lr = lane & 15, cg = lane >> 4;

    const int nwg = NBX * 16;
    const int bid = blockIdx.x;
    const int bid2 = (bid & 7) * (nwg >> 3) + (bid >> 3);
    const int bxi = bid2 % NBX, byi = bid2 / NBX;
    const int m0 = byi * 256, n0 = bxi * BN;

    const u16* __restrict__ Ag = A + (size_t)m0 * 1024;
    const u16* __restrict__ Bg = B + (size_t)n0 * 1024;

    f32x4 acc[2 * MQ][2 * NQ] = {};

#define STG_A(b, h, t)                                                              \
    do {                                                                            \
        _Pragma("unroll") for (int u = 0; u < GA; ++u) {                            \
            const int idx = u * 512 + tid;                                          \
            const int loc = idx >> 3, pp = idx & 7;                                 \
            const int row = (loc & (HA - 1)) | ((h)*HA) | ((loc / HA) * 2 * HA);    \
            gload_lds16(Ag + (size_t)row * 1024 + (t)*64 + ((pp ^ (row & 7)) << 3), \
                        &As[(((b)*2 + (h)) * CHA + idx) * 8]);                      \
        }                                                                           \
    } while (0)
#define STG_B(b, h, t)                                                              \
    do {                                                                            \
        _Pragma("unroll") for (int u = 0; u < GB; ++u) {                            \
            const int idx = u * 512 + tid;                                          \
            const int loc = idx >> 3, pp = idx & 7;                                 \
            const int row = (loc & (HB - 1)) | ((h)*HB) | ((loc / HB) * 2 * HB);    \
            gload_lds16(Bg + (size_t)row * 1024 + (t)*64 + ((pp ^ (row & 7)) << 3), \
                        &Bs[(((b)*2 + (h)) * CHB + idx) * 8]);                      \
        }                                                                           \
    } while (0)

#define LDA(bb, lm, dst)                                                            \
    _Pragma("unroll") for (int mf = 0; mf < MQ; ++mf)                               \
        _Pragma("unroll") for (int ks = 0; ks < 2; ++ks)                            \
            dst[mf][ks] = *(const s16x8*)&As[((((bb)*2 + (lm)) * CHA) +             \
                                              (mf * 16 + lr + wm * HA) * 8 +        \
                                              ((cg + ks * 4) ^ (lr & 7))) * 8];

#define LDB(bb, ln, dst)                                                            \
    _Pragma("unroll") for (int nf = 0; nf < NQ; ++nf)                               \
        _Pragma("unroll") for (int ks = 0; ks < 2; ++ks)                            \
            dst[nf][ks] = *(const s16x8*)&Bs[((((bb)*2 + (ln)) * CHB) +             \
                                              (nf * 16 + lr + wn * HB) * 8 +        \
                                              ((cg + ks * 4) ^ (lr & 7))) * 8];

#define MM(lm, ln, A_, B_)                                                          \
    __builtin_amdgcn_s_setprio(1);                                                  \
    _Pragma("unroll") for (int mf = 0; mf < MQ; ++mf)                               \
        _Pragma("unroll") for (int nf = 0; nf < NQ; ++nf)                           \
            _Pragma("unroll") for (int ks = 0; ks < 2; ++ks)                        \
                acc[(lm)*MQ + mf][(ln)*NQ + nf] = mfma16(                           \
                    A_[mf][ks], B_[nf][ks], acc[(lm)*MQ + mf][(ln)*NQ + nf]);       \
    __builtin_amdgcn_s_setprio(0);

#define BAR() asm volatile("s_barrier" ::: "memory")

    STG_A(0, 0, 0);
    STG_A(0, 1, 0);
    STG_B(0, 0, 0);
    STG_B(0, 1, 0);
    STG_A(1, 0, 1);
    STG_B(1, 0, 1);
    vmwait<GA + GB>();
    BAR();

    s16x8 va[MQ][2];
    s16x8 vb0[NQ][2], vb1[NQ][2];

#pragma unroll 1
    for (int i = 0; i < NI - 1; ++i) {
        const int t1 = 2 * i + 1, t2 = 2 * i + 2, t3 = 2 * i + 3;
        LDA(0, 0, va); LDB(0, 0, vb0); STG_A(1, 1, t1); BAR(); MM(0, 0, va, vb0);
        LDB(0, 1, vb1);                STG_B(1, 1, t1); BAR(); MM(0, 1, va, vb1);
        LDA(0, 1, va);                 STG_A(0, 0, t2); BAR(); MM(1, 0, va, vb0);
        STG_B(0, 0, t2); vmwait<GA + GB>();             BAR(); MM(1, 1, va, vb1);
        LDA(1, 0, va); LDB(1, 0, vb0); STG_A(0, 1, t2); BAR(); MM(0, 0, va, vb0);
        LDB(1, 1, vb1);                STG_B(0, 1, t2); BAR(); MM(0, 1, va, vb1);
        LDA(1, 1, va);                 STG_A(1, 0, t3); BAR(); MM(1, 0, va, vb0);
        STG_B(1, 0, t3); vmwait<GA + GB>();             BAR(); MM(1, 1, va, vb1);
    }
    LDA(0, 0, va); LDB(0, 0, vb0); STG_A(1, 1, 15); BAR(); MM(0, 0, va, vb0);
    LDB(0, 1, vb1);                STG_B(1, 1, 15); BAR(); MM(0, 1, va, vb1);
    LDA(0, 1, va);                                  BAR(); MM(1, 0, va, vb0);
    vmwait<0>();                                    BAR(); MM(1, 1, va, vb1);
    LDA(1, 0, va); LDB(1, 0, vb0); MM(0, 0, va, vb0);
    LDB(1, 1, vb1);                MM(0, 1, va, vb1);
    LDA(1, 1, va);                 MM(1, 0, va, vb0);
    MM(1, 1, va, vb1);

#undef STG_A
#undef STG_B
#undef LDA
#undef LDB
#undef MM
#undef BAR

#pragma unroll
    for (int am = 0; am < 2 * MQ; ++am) {
        const int lm = am / MQ, mf = am % MQ;
        const int rowb = m0 + wm * TM + lm * HA + mf * 16 + cg * 4;
#pragma unroll
        for (int an = 0; an < 2 * NQ; ++an) {
            const int ln = an / NQ, nf = an % NQ;
            const int col = n0 + wn * TN + ln * HB + nf * 16 + lr;
            if (EPI == 0) {
                const int which = col >> 10, hd = col & 1023;
                const int h = hd >> 6, dd = hd & 63;
                u16* dst = (which == 0) ? Qb : (which == 1) ? Kb : Vb;
                const float sc = (which == 0) ? 0.18033688011112042f : 1.0f;
#pragma unroll
                for (int r = 0; r < 4; ++r) {
                    const int tk = rowb + r;
                    const int bb2 = tk >> 10, ii = tk & 1023;
                    dst[(size_t)(((bb2 << 4) + h) * 1024 + ii) * 64 + dd] =
                        f2bf(acc[am][an][r] * sc);
                }
            } else {
                float bias;
                float* ob;
                if (col < 1024) { bias = bx[col]; ob = out + col; }
                else { bias = by[col - 1024]; ob = out + 4194304 + (col - 1024); }
#pragma unroll
                for (int r = 0; r < 4; ++r)
                    ob[(size_t)(rowb + r) * 1024] = acc[am][an][r] + bias;
            }
        }
    }
}

// ---------------- Flash attention v6 (unchanged): 3-buffer ring, head-grouped --------
__global__ __launch_bounds__(256) void attn_kernel(const u16* __restrict__ Q,
                                                   const u16* __restrict__ Kg,
                                                   const u16* __restrict__ Vt,
                                                   u16* __restrict__ xo) {
    __shared__ __align__(16) u16 Ks[3][64 * 64];
    __shared__ __align__(16) u16 Vs[3][64 * 64];
    __shared__ __align__(16) u16 Ps[4][32 * 64];
    const int tid = threadIdx.x, lane = tid & 63, w = tid >> 6;
    const int bid = blockIdx.x;
    const int bh = (bid & 7) * 8 + ((bid >> 3) & 7);  // XCD-grouped heads
    const int qblk = bid >> 6;
    const u16* Qh = Q + (size_t)bh * 65536;
    const u16* Kh = Kg + (size_t)bh * 65536;
    const u16* Vh = Vt + (size_t)bh * 65536;
    const int lr = lane & 15, cg = lane >> 4;
    const int q0 = qblk * 128 + w * 32;
    u16* Pw = &Ps[w][0];

    s16x8 qf[2][2];
#pragma unroll
    for (int qg = 0; qg < 2; ++qg)
#pragma unroll
        for (int ks = 0; ks < 2; ++ks)
            qf[qg][ks] =
                *(const s16x8*)(Qh + (size_t)(q0 + qg * 16 + lr) * 64 + ks * 32 + cg * 8);

    f32x4 o[2][4] = {};
    float l_s[2] = {0.f, 0.f};
    float m_s[2] = {-3e38f, -3e38f};
    int ba[4];
#pragma unroll
    for (int r = 0; r < 4; ++r) ba[r] = (cg * 4 + r) * 4;

#define STAGEKV(bufi, kv0)                                                               \
    do {                                                                                 \
        _Pragma("unroll") for (int i = 0; i < 2; ++i) {                                  \
            int idx = i * 256 + tid;                                                     \
            int row = idx >> 3, p = idx & 7;                                             \
            gload_lds16(Kh + (size_t)((kv0) + row) * 64 + ((p ^ (row & 7)) << 3),        \
                        &Ks[bufi][idx * 8]);                                             \
            gload_lds16(Vh + (size_t)row * 1024 + (kv0) + ((p ^ (row & 7)) << 3),        \
                        &Vs[bufi][idx * 8]);                                             \
        }                                                                                \
    } while (0)

    STAGEKV(0, 0);
    STAGEKV(1, 64);

    int buf = 0, sbuf = 2;
    for (int t = 0; t < 16; ++t) {
        if (t == 15) { vmwait<0>(); } else { vmwait<4>(); }
        asm volatile("s_barrier" ::: "memory");
        if (t < 14) STAGEKV(sbuf, (t + 2) * 64);

        f32x4 s[2][4] = {};
#pragma unroll
        for (int fn = 0; fn < 4; ++fn) {
            const int r = fn * 16 + lr;
#pragma unroll
            for (int ks = 0; ks < 2; ++ks) {
                const int c = cg + ks * 4;
                s16x8 kf = *(const s16x8*)&Ks[buf][r * 64 + ((c ^ (r & 7)) << 3)];
                s[0][fn] = mfma16(kf, qf[0][ks], s[0][fn]);
                s[1][fn] = mfma16(kf, qf[1][ks], s[1][fn]);
            }
        }

#pragma unroll
        for (int qg = 0; qg < 2; ++qg) {
            float tm = -3e38f;
#pragma unroll
            for (int fn = 0; fn < 4; ++fn)
#pragma unroll
                for (int r = 0; r < 4; ++r) tm = fmaxf(tm, s[qg][fn][r]);
            tm = fmaxf(tm, __shfl_xor(tm, 16));
            tm = fmaxf(tm, __shfl_xor(tm, 32));
            if (!__all(tm <= m_s[qg] + 8.0f)) {
                const float mn = fmaxf(m_s[qg], tm);
                const float corr = exp2a(m_s[qg] - mn);
                m_s[qg] = mn;
                l_s[qg] *= corr;
                f32x4 corr_o;
#pragma unroll
                for (int r = 0; r < 4; ++r)
                    corr_o[r] = __builtin_bit_cast(
                        float,
                        __builtin_amdgcn_ds_bpermute(ba[r], __builtin_bit_cast(int, corr)));
#pragma unroll
                for (int fd = 0; fd < 4; ++fd) o[qg][fd] *= corr_o;
            }
            const float mn = m_s[qg];
            float rs = 0.f;
            const int prow = (qg * 16 + lr) * 64;
#pragma unroll
            for (int fn = 0; fn < 4; ++fn) {
                const float p0 = exp2a(s[qg][fn][0] - mn);
                const float p1 = exp2a(s[qg][fn][1] - mn);
                const float p2 = exp2a(s[qg][fn][2] - mn);
                const float p3 = exp2a(s[qg][fn][3] - mn);
                rs += (p0 + p1) + (p2 + p3);
                uint2 dd;
                dd.x = cvtpk(p0, p1);
                dd.y = cvtpk(p2, p3);
                *(uint2*)(Pw + prow + (((2 * fn + (cg >> 1)) ^ (lr & 7)) << 3) +
                          ((cg & 1) << 2)) = dd;
            }
            rs += __shfl_xor(rs, 16);
            rs += __shfl_xor(rs, 32);
            l_s[qg] += rs;
        }

        s16x8 pf[2][2];
#pragma unroll
        for (int qg = 0; qg < 2; ++qg)
#pragma unroll
            for (int ks = 0; ks < 2; ++ks)
                pf[qg][ks] = *(const s16x8*)(Pw + (qg * 16 + lr) * 64 +
                                             (((4 * ks + cg) ^ (lr & 7)) << 3));
#pragma unroll
        for (int fd = 0; fd < 4; ++fd) {
            const int rr = fd * 16 + lr;
#pragma unroll
            for (int ks = 0; ks < 2; ++ks) {
                const int c = cg + ks * 4;
                s16x8 vf = *(const s16x8*)&Vs[buf][rr * 64 + ((c ^ (rr & 7)) << 3)];
                o[0][fd] = mfma16(pf[0][ks], vf, o[0][fd]);
                o[1][fd] = mfma16(pf[1][ks], vf, o[1][fd]);
            }
        }
        buf = (buf == 2) ? 0 : buf + 1;
        sbuf = (sbuf == 2) ? 0 : sbuf + 1;
    }
#undef STAGEKV

    const int b = bh >> 4, h = bh & 15;
#pragma unroll
    for (int qg = 0; qg < 2; ++qg) {
        f32x4 inv;
#pragma unroll
        for (int r = 0; r < 4; ++r) {
            const float lq = __builtin_bit_cast(
                float, __builtin_amdgcn_ds_bpermute(ba[r], __builtin_bit_cast(int, l_s[qg])));
            inv[r] = 1.0f / lq;
        }
#pragma unroll
        for (int r = 0; r < 4; ++r) {
            const int qrow = q0 + qg * 16 + cg * 4 + r;
#pragma unroll
            for (int fd = 0; fd < 4; ++fd)
                xo[(size_t)(b * 1024 + qrow) * 1024 + h * 64 + fd * 16 + lr] =
                    f2bf(o[qg][fd][r] * inv[r]);
        }
    }
}

extern "C" void kernel_launch(void* const* d_in, const int* in_sizes, int n_in,
                              void* d_out, int out_size, void* d_ws, size_t ws_size,
                              hipStream_t stream) {
    const float* x = (const float*)d_in[0];
    const float* gx = (const float*)d_in[2];
    const float* bxv = (const float*)d_in[3];
    const float* Wqkv = (const float*)d_in[6];
    const float* Woutx = (const float*)d_in[8];
    const float* boutx = (const float*)d_in[9];
    const float* Wouty = (const float*)d_in[10];
    const float* bouty = (const float*)d_in[11];
    float* out = (float*)d_out;

    u16* ws = (u16*)d_ws;
    u16* xn = ws;                           // 4096*1024
    u16* wqkv_t = xn + 4096 * 1024;         // 3072*1024
    u16* wout_t = wqkv_t + 3072 * 1024;     // 2048*1024
    u16* Qb = wout_t + 2048 * 1024;         // 64*1024*64
    u16* Kb = Qb + 64 * 1024 * 64;
    u16* Vtb = Kb + 64 * 1024 * 64;
    u16* xob = Vtb + 64 * 1024 * 64;        // 4096*1024

    prep_kernel<<<4096 + 768 + 512, 256, 0, stream>>>(x, gx, bxv, xn, Wqkv, Woutx,
                                                      Wouty, wqkv_t, wout_t);
    gemm1k<<<256, 512, 0, stream>>>(xn, wqkv_t, Qb, Kb, Vtb);
    attn_kernel<<<512, 256, 0, stream>>>(Qb, Kb, Vtb, xob);
    gemm8<128, 4, 1><<<256, 512, 0, stream>>>(xob, wout_t, nullptr, nullptr, nullptr,
                                              boutx, bouty, out, 16);
}